// Round 13
// baseline (1233.519 us; speedup 1.0000x reference)
//
#include <hip/hip_runtime.h>

#define NTOK 49
#define CDIM 192
#define NHEAD 6
#define HDIM 32

typedef float f32x4 __attribute__((ext_vector_type(4), may_alias));
typedef short b16x8 __attribute__((ext_vector_type(8), may_alias));
typedef short b16x4 __attribute__((ext_vector_type(4), may_alias));
typedef unsigned u32x2 __attribute__((ext_vector_type(2), may_alias));
typedef unsigned u32x4 __attribute__((ext_vector_type(4), may_alias));

__device__ __forceinline__ f32x4 MFMA(b16x8 a, b16x8 b, f32x4 c) {
  return __builtin_amdgcn_mfma_f32_16x16x32_bf16(a, b, c, 0, 0, 0);
}

// Scalar RNE f32->bf16 (for scalar transpose stores). Verified R2-R12.
__device__ __forceinline__ short f2bf(float f) {
  unsigned u = __builtin_bit_cast(unsigned, f);
  u += 0x7FFFu + ((u >> 16) & 1u);
  return (short)(u >> 16);
}

// Packed RNE pair-convert: 1 instruction for 2 values (vs 3 VALU ops/value).
// NOT R10's __bf16 cast (that scalarized vector builds and spilled 1.5 GB).
__device__ __forceinline__ unsigned cvt2(float lo, float hi) {
  unsigned r;
  asm("v_cvt_pk_bf16_f32 %0, %1, %2" : "=v"(r) : "v"(lo), "v"(hi));
  return r;
}
__device__ __forceinline__ b16x4 pack4(float a, float b, float c, float d) {
  return __builtin_bit_cast(b16x4, (u32x2){cvt2(a, b), cvt2(c, d)});
}

// XOR swizzle for [64][192] bf16 tiles: 8-short (16B) granules, bijective
// within each 8-row stripe; 16-row-column b128 reads 2-way (free).
__device__ __forceinline__ int swz(int row, int col) {
  return row * CDIM + (col ^ ((row & 7) << 3));
}

// ---- prep 1: fp32 weights -> bf16 ws. Wq pre-scaled by D^-0.5 ----
__global__ void prep_w(const float* __restrict__ Wq, const float* __restrict__ Wkv,
                       const float* __restrict__ Wo, short* __restrict__ wsW) {
  const float scale = 0.17677669529663687f;
  int i = blockIdx.x * 256 + threadIdx.x;
  if (i >= 147456) return;
  float v;
  if (i < 36864)        v = Wq[i] * scale;
  else if (i < 110592)  v = Wkv[i - 36864];
  else                  v = Wo[i - 110592];
  wsW[i] = f2bf(v);
}

// ---- prep 2: rel-pos-bias table [H][49][49] f32 (57.6 KB, stays L2-hot) ----
__global__ void prep_bias(const float* __restrict__ rpb, float* __restrict__ bias_t) {
  int idx = blockIdx.x * 256 + threadIdx.x;
  if (idx >= NHEAD * NTOK * NTOK) return;
  int h = idx / (NTOK * NTOK);
  int p = idx % (NTOK * NTOK);
  int i = p / NTOK, j = p % NTOK;
  int ci = (i / 7) * 13 + (i % 7);
  int jj = 48 - j;
  int cj = (jj / 7) * 13 + (jj % 7);
  bias_t[idx] = rpb[(ci + cj) * NHEAD + h];
}

// Fused window-MSA, 6-barrier edition (champion R12 minus q-staging round-trip).
// 1 window/block, 8 waves, LDS 75264 B (2 blocks/CU; TLP reg-capped at
// 4 waves/SIMD by VGPR64+AGPR64 — see occupancy law, R6-R12 fits).
// Phase chain: [q direct-global -> q-proj -> qh bounce (own-wave, no barrier)]
// B1 [kv stage] B2 [kv-proj] B3 [attention, P per-wave in dead SH] B4
// [x -> KH] B5 [o-proj -> BF rolling] B6 [coalesced stores].
__global__ __attribute__((amdgpu_flat_work_group_size(512, 512),
                          amdgpu_waves_per_eu(3))) void wmsa_kernel(
    const float* __restrict__ qg, const float* __restrict__ kvg,
    const float* __restrict__ maskg, const float* __restrict__ bq,
    const float* __restrict__ bkv, const float* __restrict__ bo,
    const short* __restrict__ wsW, const float* __restrict__ bias_t,
    float* __restrict__ outg, int nW) {
  __shared__ short lds[37632];     // 75264 B
  short* SH = lds;                 // [64][192] swizzled: qh bounce -> kv -> P
  short* VT = lds + 12288;         // [192][68] vhT[c][token]
  short* KH = lds + 25344;         // [64][192] swizzled: kh -> x
  float* BF = (float*)lds;         // epilogue bounce [49][204] f32 (40 KB)

  const int b = blockIdx.x;
  const int tid = threadIdx.x;
  const int w = tid >> 6;          // wave 0..7
  const int lane = tid & 63;
  const int l15 = lane & 15;
  const int lg = lane >> 4;
  const int R = w >> 1, hw = w & 1, h0 = hw * 3;
  const float scale = 0.17677669529663687f;
  const f32x4 zero4 = {0.f, 0.f, 0.f, 0.f};

  const short* WqB = wsW;
  const short* WkvB = wsW + 36864;
  const short* WoB = wsW + 110592;

  const float* qsrc = qg + (size_t)b * (NTOK * CDIM);
  const float* kvsrc = kvg + (size_t)b * (NTOK * CDIM);

  const int qrow = R * 16 + l15;
  const int qc = qrow > 48 ? 48 : qrow;  // pad lanes -> row 48 (outputs unused)

  // ---- issue kv loads up front (consumed after q-proj; hides HBM latency) ----
  f32x4 kvreg[6];
#pragma unroll
  for (int it = 0; it < 6; ++it) {
    int idx = tid + it * 512;
    int r = idx / 48, c4 = idx % 48;
    kvreg[it] = (r < NTOK) ? *(const f32x4*)(kvsrc + r * CDIM + c4 * 4) : zero4;
  }

  // ---- q-projection: direct-global A-fragments (R8-verified mechanism) ----
  b16x8 aq6[6];
#pragma unroll
  for (int kk = 0; kk < 6; ++kk) {
    f32x4 lo = *(const f32x4*)(qsrc + qc * CDIM + kk * 32 + lg * 8);
    f32x4 hi = *(const f32x4*)(qsrc + qc * CDIM + kk * 32 + lg * 8 + 4);
    aq6[kk] = __builtin_bit_cast(
        b16x8, (u32x4){cvt2(lo[0], lo[1]), cvt2(lo[2], lo[3]),
                       cvt2(hi[0], hi[1]), cvt2(hi[2], hi[3])});
  }
  f32x4 qacc[6];
#pragma unroll
  for (int t = 0; t < 6; ++t) qacc[t] = zero4;
#pragma unroll
  for (int t = 0; t < 6; ++t) {
    const int col = (hw * 6 + t) * 16 + l15;
#pragma unroll
    for (int kk = 0; kk < 6; ++kk) {
      b16x8 bw = *(const b16x8*)(WqB + col * CDIM + kk * 32 + lg * 8);
      qacc[t] = MFMA(aq6[kk], bw, qacc[t]);
    }
  }
  // qh -> own SH region (rows R*16..+15, cols hw*96..+95); own-wave LDS RAW
  // is ordered, so the aq readback needs no barrier.
#pragma unroll
  for (int t = 0; t < 6; ++t) {
    const int col = (hw * 6 + t) * 16 + l15;
    const float bias = bq[col] * scale;
#pragma unroll
    for (int r = 0; r < 4; ++r)
      SH[swz(R * 16 + lg * 4 + r, hw * 96 + t * 16 + l15)] = f2bf(qacc[t][r] + bias);
  }
  b16x8 aq[3];
#pragma unroll
  for (int hh = 0; hh < 3; ++hh)
    aq[hh] = *(const b16x8*)(SH + swz(R * 16 + l15, hw * 96 + hh * 32 + lg * 8));
  __syncthreads();  // B1: all qh bounces done; SH free for kv

  // ---- stage kv (from regs) -> SH ----
#pragma unroll
  for (int it = 0; it < 6; ++it) {
    int idx = tid + it * 512;
    int r = idx / 48, c4 = idx % 48;
    *(b16x4*)(SH + swz(r, c4 * 4)) =
        pack4(kvreg[it][0], kvreg[it][1], kvreg[it][2], kvreg[it][3]);
  }
  __syncthreads();  // B2: kv staged

  // ---- kv projection: 24 col-tiles, wave w -> nt = w*3 + {0,1,2} ----
#pragma unroll
  for (int jj = 0; jj < 3; ++jj) {
    const int nt = w * 3 + jj;
    const int col = nt * 16 + l15;  // 0..383
    f32x4 acc[4];
#pragma unroll
    for (int m = 0; m < 4; ++m) acc[m] = zero4;
#pragma unroll
    for (int kk = 0; kk < 6; ++kk) {
      b16x8 bw = *(const b16x8*)(WkvB + col * CDIM + kk * 32 + lg * 8);
#pragma unroll
      for (int m = 0; m < 4; ++m) {
        b16x8 a = *(const b16x8*)(SH + swz(m * 16 + l15, kk * 32 + lg * 8));
        acc[m] = MFMA(a, bw, acc[m]);
      }
    }
    const float bias = bkv[col];
    if (col < CDIM) {  // K half -> KH[token][col]
#pragma unroll
      for (int m = 0; m < 4; ++m)
#pragma unroll
        for (int r = 0; r < 4; ++r)
          KH[swz(m * 16 + lg * 4 + r, col)] = f2bf(acc[m][r] + bias);
    } else {  // V half -> VT[c][token]
      const int c = col - CDIM;
#pragma unroll
      for (int m = 0; m < 4; ++m)
        *(b16x4*)(VT + c * 68 + m * 16 + lg * 4) =
            pack4(acc[m][0] + bias, acc[m][1] + bias, acc[m][2] + bias,
                  acc[m][3] + bias);
    }
  }
  __syncthreads();  // B3: kh/vT ready; SH kv dead

  // ---- attention: wave w -> rows R*16..+15, heads h0..h0+2 ----
  const float* maskw = maskg + (size_t)(b % nW) * (NTOK * NTOK);
  float maskv[4][4];
#pragma unroll
  for (int nt = 0; nt < 4; ++nt) {
    const int cgl = nt * 16 + l15;
#pragma unroll
    for (int r = 0; r < 4; ++r) {
      const int rw = R * 16 + lg * 4 + r;
      maskv[nt][r] = (rw < NTOK && cgl < NTOK) ? maskw[rw * NTOK + cgl] : 0.f;
    }
  }

  f32x4 xh[3][2];
#pragma unroll
  for (int hh = 0; hh < 3; ++hh) {
    xh[hh][0] = zero4;
    xh[hh][1] = zero4;
  }
#pragma unroll
  for (int hh = 0; hh < 3; ++hh) {
    const int h = h0 + hh;
    f32x4 L[4];
#pragma unroll
    for (int nt = 0; nt < 4; ++nt) {
      b16x8 bk = *(const b16x8*)(KH + swz(nt * 16 + l15, h * 32 + lg * 8));
      L[nt] = MFMA(aq[hh], bk, zero4);
    }
    const float* bt = bias_t + h * (NTOK * NTOK);
#pragma unroll
    for (int nt = 0; nt < 4; ++nt) {
      const int cgl = nt * 16 + l15;
#pragma unroll
      for (int r = 0; r < 4; ++r) {
        const int rw = R * 16 + lg * 4 + r;
        if (rw < NTOK && cgl < NTOK) L[nt][r] += bt[rw * NTOK + cgl] + maskv[nt][r];
        else                          L[nt][r] = -1e9f;
      }
    }
#pragma unroll
    for (int r = 0; r < 4; ++r) {
      float m = fmaxf(fmaxf(L[0][r], L[1][r]), fmaxf(L[2][r], L[3][r]));
      m = fmaxf(m, __shfl_xor(m, 1));
      m = fmaxf(m, __shfl_xor(m, 2));
      m = fmaxf(m, __shfl_xor(m, 4));
      m = fmaxf(m, __shfl_xor(m, 8));
      float p0 = __expf(L[0][r] - m), p1 = __expf(L[1][r] - m);
      float p2 = __expf(L[2][r] - m), p3 = __expf(L[3][r] - m);
      float s = p0 + p1 + p2 + p3;
      s += __shfl_xor(s, 1);
      s += __shfl_xor(s, 2);
      s += __shfl_xor(s, 4);
      s += __shfl_xor(s, 8);
      const float is = 1.0f / s;
      L[0][r] = p0 * is; L[1][r] = p1 * is; L[2][r] = p2 * is; L[3][r] = p3 * is;
    }
    // P -> SH own region (rows R*16..+15, cols hw*96..+63), then PV
#pragma unroll
    for (int nt = 0; nt < 4; ++nt)
#pragma unroll
      for (int r = 0; r < 4; ++r)
        SH[swz(R * 16 + lg * 4 + r, hw * 96 + nt * 16 + l15)] = f2bf(L[nt][r]);
#pragma unroll
    for (int kk = 0; kk < 2; ++kk) {
      b16x8 ap = *(const b16x8*)(SH + swz(R * 16 + l15, hw * 96 + kk * 32 + lg * 8));
#pragma unroll
      for (int nv = 0; nv < 2; ++nv) {
        b16x8 bv = *(const b16x8*)(VT + (h * 32 + nv * 16 + l15) * 68 + kk * 32 + lg * 8);
        xh[hh][nv] = MFMA(ap, bv, xh[hh][nv]);
      }
    }
  }
  __syncthreads();  // B4: all KH (kh) + VT reads done
  // ---- x -> KH ----
#pragma unroll
  for (int hh = 0; hh < 3; ++hh)
#pragma unroll
    for (int nv = 0; nv < 2; ++nv)
#pragma unroll
      for (int r = 0; r < 4; ++r)
        KH[swz(R * 16 + lg * 4 + r, (h0 + hh) * 32 + nv * 16 + l15)] =
            f2bf(xh[hh][nv][r]);
  __syncthreads();  // B5: x ready (SH, VT dead -> bounce region)

  // ---- output projection -> f32 bounce (stride 204), rolling acc ----
#pragma unroll
  for (int t = 0; t < 6; ++t) {
    const int pid = w * 6 + t;
    const int j = pid >> 2, m = pid & 3;
    const int col = j * 16 + l15;
    f32x4 oacc = zero4;
#pragma unroll
    for (int kk = 0; kk < 6; ++kk) {
      b16x8 a = *(const b16x8*)(KH + swz(m * 16 + l15, kk * 32 + lg * 8));
      b16x8 bw = *(const b16x8*)(WoB + col * CDIM + kk * 32 + lg * 8);
      oacc = MFMA(a, bw, oacc);
    }
    const float bias = bo[col];
#pragma unroll
    for (int r = 0; r < 4; ++r) {
      const int row = m * 16 + lg * 4 + r;
      if (row < NTOK) BF[row * 204 + col] = oacc[r] + bias;
    }
  }
  __syncthreads();  // B6: bounce ready

  // ---- fully coalesced output stores (16B/lane contiguous) ----
  float* dst = outg + (size_t)b * (NTOK * CDIM);
#pragma unroll
  for (int t = 0; t < 5; ++t) {
    int idx = tid + t * 512;
    if (idx < NTOK * 48) {
      int row = idx / 48, c4 = idx % 48;
      f32x4 v = *(const f32x4*)(BF + row * 204 + c4 * 4);
      *(f32x4*)(dst + row * CDIM + c4 * 4) = v;
    }
  }
}

extern "C" void kernel_launch(void* const* d_in, const int* in_sizes, int n_in,
                              void* d_out, int out_size, void* d_ws, size_t ws_size,
                              hipStream_t stream) {
  const float* q = (const float*)d_in[0];
  const float* kv = (const float*)d_in[1];
  const float* mask = (const float*)d_in[2];
  const float* Wq = (const float*)d_in[3];
  const float* bq = (const float*)d_in[4];
  const float* Wkv = (const float*)d_in[5];
  const float* bkv = (const float*)d_in[6];
  const float* Wo = (const float*)d_in[7];
  const float* bo = (const float*)d_in[8];
  const float* rpb = (const float*)d_in[9];
  short* wsW = (short*)d_ws;
  float* bias_t = (float*)((char*)d_ws + 294912);  // [6][49][49] f32, 57.6 KB

  const int B = in_sizes[0] / (NTOK * CDIM);
  const int nW = in_sizes[2] / (NTOK * NTOK);

  prep_w<<<576, 256, 0, stream>>>(Wq, Wkv, Wo, wsW);
  prep_bias<<<57, 256, 0, stream>>>(rpb, bias_t);
  wmsa_kernel<<<B, 512, 0, stream>>>(q, kv, mask, bq, bkv, bo, wsW, bias_t,
                                     (float*)d_out, nW);
}

// Round 14
// 888.975 us; speedup vs baseline: 1.3876x; 1.3876x over previous
//
#include <hip/hip_runtime.h>

#define NTOK 49
#define CDIM 192
#define NHEAD 6
#define HDIM 32

typedef float f32x4 __attribute__((ext_vector_type(4), may_alias));
typedef short b16x8 __attribute__((ext_vector_type(8), may_alias));
typedef short b16x4 __attribute__((ext_vector_type(4), may_alias));

__device__ __forceinline__ f32x4 MFMA(b16x8 a, b16x8 b, f32x4 c) {
  return __builtin_amdgcn_mfma_f32_16x16x32_bf16(a, b, c, 0, 0, 0);
}

__device__ __forceinline__ short f2bf(float f) {
  unsigned u = __builtin_bit_cast(unsigned, f);
  u += 0x7FFFu + ((u >> 16) & 1u);  // round-to-nearest-even
  return (short)(u >> 16);
}

// XOR swizzle for [64][192] bf16 tiles: 8-short (16B) granules, bijective
// within each 8-row stripe; makes 16-row-column b128 reads 2-way (free).
__device__ __forceinline__ int swz(int row, int col) {
  return row * CDIM + (col ^ ((row & 7) << 3));
}

// ---- prep 1: fp32 weights -> bf16 ws. Wq pre-scaled by D^-0.5 ----
// ws shorts: [0,36864) Wq | [36864,110592) Wkv | [110592,147456) Wo
__global__ void prep_w(const float* __restrict__ Wq, const float* __restrict__ Wkv,
                       const float* __restrict__ Wo, short* __restrict__ wsW) {
  const float scale = 0.17677669529663687f;
  int i = blockIdx.x * 256 + threadIdx.x;
  if (i >= 147456) return;
  float v;
  if (i < 36864)        v = Wq[i] * scale;
  else if (i < 110592)  v = Wkv[i - 36864];
  else                  v = Wo[i - 110592];
  wsW[i] = f2bf(v);
}

// ---- prep 2: rel-pos-bias table [H][49][49] f32 (57.6 KB, stays L2-hot) ----
__global__ void prep_bias(const float* __restrict__ rpb, float* __restrict__ bias_t) {
  int idx = blockIdx.x * 256 + threadIdx.x;
  if (idx >= NHEAD * NTOK * NTOK) return;
  int h = idx / (NTOK * NTOK);
  int p = idx % (NTOK * NTOK);
  int i = p / NTOK, j = p % NTOK;
  int ci = (i / 7) * 13 + (i % 7);
  int jj = 48 - j;
  int cj = (jj / 7) * 13 + (jj % 7);
  bias_t[idx] = rpb[(ci + cj) * NHEAD + h];
}

// Fused window-MSA — R12 champion structure (890 us, zero spill, VGPR=64).
// REGISTER CLIFF (R6-R13 law): waves/SIMD ~ 512/(VGPRgranule+AGPR); VGPR must
// stay EXACTLY <=64 — 68 VGPR halved occupancy (R13). Do not add live state.
// Single rider vs R12: s_setprio(1) around attention MFMA clusters only
// (T5, m191 regime: independent blocks at different phases on one CU).
__global__ __attribute__((amdgpu_flat_work_group_size(512, 512),
                          amdgpu_waves_per_eu(3))) void wmsa_kernel(
    const float* __restrict__ qg, const float* __restrict__ kvg,
    const float* __restrict__ maskg, const float* __restrict__ bq,
    const float* __restrict__ bkv, const float* __restrict__ bo,
    const short* __restrict__ wsW, const float* __restrict__ bias_t,
    float* __restrict__ outg, int nW) {
  __shared__ short lds[37632];     // 75264 B
  short* SH = lds;                 // [64][192] swizzled
  short* VT = lds + 12288;         // [192][68] vhT[c][token]
  short* KH = lds + 25344;         // [64][192] swizzled
  float* BF = (float*)lds;         // epilogue bounce [49][204] f32 (40 KB)

  const int b = blockIdx.x;
  const int tid = threadIdx.x;
  const int w = tid >> 6;          // wave 0..7
  const int lane = tid & 63;
  const int l15 = lane & 15;
  const int lg = lane >> 4;
  const int R = w >> 1, hw = w & 1, h0 = hw * 3;
  const float scale = 0.17677669529663687f;
  const f32x4 zero4 = {0.f, 0.f, 0.f, 0.f};

  const short* WqB = wsW;
  const short* WkvB = wsW + 36864;
  const short* WoB = wsW + 110592;

  const float* qsrc = qg + (size_t)b * (NTOK * CDIM);
  const float* kvsrc = kvg + (size_t)b * (NTOK * CDIM);

  // ---- issue q and kv loads up front (HBM latency hidden under staging+q-proj) ----
  f32x4 qv[6], kvreg[6];
#pragma unroll
  for (int it = 0; it < 6; ++it) {
    int idx = tid + it * 512;
    int r = idx / 48, c4 = idx % 48;
    qv[it] = (r < NTOK) ? *(const f32x4*)(qsrc + r * CDIM + c4 * 4) : zero4;
  }
#pragma unroll
  for (int it = 0; it < 6; ++it) {
    int idx = tid + it * 512;
    int r = idx / 48, c4 = idx % 48;
    kvreg[it] = (r < NTOK) ? *(const f32x4*)(kvsrc + r * CDIM + c4 * 4) : zero4;
  }
  // ---- stage q -> SH bf16 (rows 49..63 zero) ----
#pragma unroll
  for (int it = 0; it < 6; ++it) {
    int idx = tid + it * 512;
    int r = idx / 48, c4 = idx % 48;
    b16x4 o = {f2bf(qv[it][0]), f2bf(qv[it][1]), f2bf(qv[it][2]), f2bf(qv[it][3])};
    *(b16x4*)(SH + swz(r, c4 * 4)) = o;
  }
  __syncthreads();  // B1: q staged

  // ---- q projection: wave computes exactly its own attention q-tile ----
  // rows m=R (16 rows), col-tiles j = hw*6 + t (96 cols = heads h0..h0+2)
  f32x4 qacc[6];
#pragma unroll
  for (int t = 0; t < 6; ++t) qacc[t] = zero4;
  {
    b16x8 aq6[6];
#pragma unroll
    for (int kk = 0; kk < 6; ++kk)
      aq6[kk] = *(const b16x8*)(SH + swz(R * 16 + l15, kk * 32 + lg * 8));
#pragma unroll
    for (int t = 0; t < 6; ++t) {
      const int col = (hw * 6 + t) * 16 + l15;
#pragma unroll
      for (int kk = 0; kk < 6; ++kk) {
        b16x8 bw = *(const b16x8*)(WqB + col * CDIM + kk * 32 + lg * 8);
        qacc[t] = MFMA(aq6[kk], bw, qacc[t]);
      }
    }
  }
  __syncthreads();  // B2: all q reads from SH done

  // ---- qh -> own SH region (rows R*16..+15, cols hw*96..+95), read aq ----
#pragma unroll
  for (int t = 0; t < 6; ++t) {
    const int col = (hw * 6 + t) * 16 + l15;
    const float bias = bq[col] * scale;
#pragma unroll
    for (int r = 0; r < 4; ++r)
      SH[swz(R * 16 + lg * 4 + r, hw * 96 + t * 16 + l15)] = f2bf(qacc[t][r] + bias);
  }
  b16x8 aq[3];
#pragma unroll
  for (int hh = 0; hh < 3; ++hh)
    aq[hh] = *(const b16x8*)(SH + swz(R * 16 + l15, hw * 96 + hh * 32 + lg * 8));
  __syncthreads();  // B3: qh reads done everywhere

  // ---- stage kv (from regs) -> SH ----
#pragma unroll
  for (int it = 0; it < 6; ++it) {
    int idx = tid + it * 512;
    int r = idx / 48, c4 = idx % 48;
    b16x4 o = {f2bf(kvreg[it][0]), f2bf(kvreg[it][1]), f2bf(kvreg[it][2]),
               f2bf(kvreg[it][3])};
    *(b16x4*)(SH + swz(r, c4 * 4)) = o;
  }
  __syncthreads();  // B4: kv staged

  // ---- kv projection: 24 col-tiles, wave w -> nt = w*3 + {0,1,2} ----
#pragma unroll
  for (int jj = 0; jj < 3; ++jj) {
    const int nt = w * 3 + jj;
    const int col = nt * 16 + l15;  // 0..383
    f32x4 acc[4];
#pragma unroll
    for (int m = 0; m < 4; ++m) acc[m] = zero4;
#pragma unroll
    for (int kk = 0; kk < 6; ++kk) {
      b16x8 bw = *(const b16x8*)(WkvB + col * CDIM + kk * 32 + lg * 8);
#pragma unroll
      for (int m = 0; m < 4; ++m) {
        b16x8 a = *(const b16x8*)(SH + swz(m * 16 + l15, kk * 32 + lg * 8));
        acc[m] = MFMA(a, bw, acc[m]);
      }
    }
    const float bias = bkv[col];
    if (col < CDIM) {  // K half -> KH[token][col]
#pragma unroll
      for (int m = 0; m < 4; ++m)
#pragma unroll
        for (int r = 0; r < 4; ++r)
          KH[swz(m * 16 + lg * 4 + r, col)] = f2bf(acc[m][r] + bias);
    } else {  // V half -> VT[c][token]
      const int c = col - CDIM;
#pragma unroll
      for (int m = 0; m < 4; ++m) {
        b16x4 o = {f2bf(acc[m][0] + bias), f2bf(acc[m][1] + bias),
                   f2bf(acc[m][2] + bias), f2bf(acc[m][3] + bias)};
        *(b16x4*)(VT + c * 68 + m * 16 + lg * 4) = o;
      }
    }
  }
  __syncthreads();  // B5: kh/vT ready; SH kv dead

  // ---- attention: wave w -> rows R*16..+15, heads h0..h0+2 ----
  const float* maskw = maskg + (size_t)(b % nW) * (NTOK * NTOK);
  float maskv[4][4];
#pragma unroll
  for (int nt = 0; nt < 4; ++nt) {
    const int cgl = nt * 16 + l15;
#pragma unroll
    for (int r = 0; r < 4; ++r) {
      const int rw = R * 16 + lg * 4 + r;
      maskv[nt][r] = (rw < NTOK && cgl < NTOK) ? maskw[rw * NTOK + cgl] : 0.f;
    }
  }

  f32x4 xh[3][2];
#pragma unroll
  for (int hh = 0; hh < 3; ++hh) {
    xh[hh][0] = zero4;
    xh[hh][1] = zero4;
  }
#pragma unroll
  for (int hh = 0; hh < 3; ++hh) {
    const int h = h0 + hh;
    f32x4 L[4];
    __builtin_amdgcn_s_setprio(1);  // T5: favor this wave's matrix pipe
#pragma unroll
    for (int nt = 0; nt < 4; ++nt) {
      b16x8 bk = *(const b16x8*)(KH + swz(nt * 16 + l15, h * 32 + lg * 8));
      L[nt] = MFMA(aq[hh], bk, zero4);
    }
    __builtin_amdgcn_s_setprio(0);
    const float* bt = bias_t + h * (NTOK * NTOK);
#pragma unroll
    for (int nt = 0; nt < 4; ++nt) {
      const int cgl = nt * 16 + l15;
#pragma unroll
      for (int r = 0; r < 4; ++r) {
        const int rw = R * 16 + lg * 4 + r;
        if (rw < NTOK && cgl < NTOK) L[nt][r] += bt[rw * NTOK + cgl] + maskv[nt][r];
        else                          L[nt][r] = -1e9f;
      }
    }
#pragma unroll
    for (int r = 0; r < 4; ++r) {
      float m = fmaxf(fmaxf(L[0][r], L[1][r]), fmaxf(L[2][r], L[3][r]));
      m = fmaxf(m, __shfl_xor(m, 1));
      m = fmaxf(m, __shfl_xor(m, 2));
      m = fmaxf(m, __shfl_xor(m, 4));
      m = fmaxf(m, __shfl_xor(m, 8));
      float p0 = __expf(L[0][r] - m), p1 = __expf(L[1][r] - m);
      float p2 = __expf(L[2][r] - m), p3 = __expf(L[3][r] - m);
      float s = p0 + p1 + p2 + p3;
      s += __shfl_xor(s, 1);
      s += __shfl_xor(s, 2);
      s += __shfl_xor(s, 4);
      s += __shfl_xor(s, 8);
      const float is = 1.0f / s;
      L[0][r] = p0 * is; L[1][r] = p1 * is; L[2][r] = p2 * is; L[3][r] = p3 * is;
    }
    // P -> SH own region (rows R*16..+15, cols hw*96..+63), then PV
#pragma unroll
    for (int nt = 0; nt < 4; ++nt)
#pragma unroll
      for (int r = 0; r < 4; ++r)
        SH[swz(R * 16 + lg * 4 + r, hw * 96 + nt * 16 + l15)] = f2bf(L[nt][r]);
    __builtin_amdgcn_s_setprio(1);  // T5: PV cluster
#pragma unroll
    for (int kk = 0; kk < 2; ++kk) {
      b16x8 ap = *(const b16x8*)(SH + swz(R * 16 + l15, hw * 96 + kk * 32 + lg * 8));
#pragma unroll
      for (int nv = 0; nv < 2; ++nv) {
        b16x8 bv = *(const b16x8*)(VT + (h * 32 + nv * 16 + l15) * 68 + kk * 32 + lg * 8);
        xh[hh][nv] = MFMA(ap, bv, xh[hh][nv]);
      }
    }
    __builtin_amdgcn_s_setprio(0);
  }
  __syncthreads();  // B6: all KH (kh) reads done
  // ---- x -> KH ----
#pragma unroll
  for (int hh = 0; hh < 3; ++hh)
#pragma unroll
    for (int nv = 0; nv < 2; ++nv)
#pragma unroll
      for (int r = 0; r < 4; ++r)
        KH[swz(R * 16 + lg * 4 + r, (h0 + hh) * 32 + nv * 16 + l15)] =
            f2bf(xh[hh][nv][r]);
  __syncthreads();  // B7: x ready (SH, VT dead -> bounce region)

  // ---- output projection -> f32 bounce (stride 204) ----
#pragma unroll
  for (int t = 0; t < 6; ++t) {
    const int pid = w * 6 + t;
    const int j = pid >> 2, m = pid & 3;
    const int col = j * 16 + l15;
    f32x4 oacc = zero4;
#pragma unroll
    for (int kk = 0; kk < 6; ++kk) {
      b16x8 a = *(const b16x8*)(KH + swz(m * 16 + l15, kk * 32 + lg * 8));
      b16x8 bw = *(const b16x8*)(WoB + col * CDIM + kk * 32 + lg * 8);
      oacc = MFMA(a, bw, oacc);
    }
    const float bias = bo[col];
#pragma unroll
    for (int r = 0; r < 4; ++r) {
      const int row = m * 16 + lg * 4 + r;
      if (row < NTOK) BF[row * 204 + col] = oacc[r] + bias;
    }
  }
  __syncthreads();  // B8: bounce ready

  // ---- fully coalesced output stores (16B/lane contiguous) ----
  float* dst = outg + (size_t)b * (NTOK * CDIM);
#pragma unroll
  for (int t = 0; t < 5; ++t) {
    int idx = tid + t * 512;
    if (idx < NTOK * 48) {
      int row = idx / 48, c4 = idx % 48;
      f32x4 v = *(const f32x4*)(BF + row * 204 + c4 * 4);
      *(f32x4*)(dst + row * CDIM + c4 * 4) = v;
    }
  }
}

extern "C" void kernel_launch(void* const* d_in, const int* in_sizes, int n_in,
                              void* d_out, int out_size, void* d_ws, size_t ws_size,
                              hipStream_t stream) {
  const float* q = (const float*)d_in[0];
  const float* kv = (const float*)d_in[1];
  const float* mask = (const float*)d_in[2];
  const float* Wq = (const float*)d_in[3];
  const float* bq = (const float*)d_in[4];
  const float* Wkv = (const float*)d_in[5];
  const float* bkv = (const float*)d_in[6];
  const float* Wo = (const float*)d_in[7];
  const float* bo = (const float*)d_in[8];
  const float* rpb = (const float*)d_in[9];
  short* wsW = (short*)d_ws;
  float* bias_t = (float*)((char*)d_ws + 294912);  // [6][49][49] f32, 57.6 KB

  const int B = in_sizes[0] / (NTOK * CDIM);
  const int nW = in_sizes[2] / (NTOK * NTOK);

  prep_w<<<576, 256, 0, stream>>>(Wq, Wkv, Wo, wsW);
  prep_bias<<<57, 256, 0, stream>>>(rpb, bias_t);
  wmsa_kernel<<<B, 512, 0, stream>>>(q, kv, mask, bq, bkv, bo, wsW, bias_t,
                                     (float*)d_out, nW);
}

// Round 15
// 783.836 us; speedup vs baseline: 1.5737x; 1.1341x over previous
//
#include <hip/hip_runtime.h>

#define NTOK 49
#define CDIM 192
#define NHEAD 6
#define HDIM 32

typedef float f32x4 __attribute__((ext_vector_type(4), may_alias));
typedef float f32x4u __attribute__((ext_vector_type(4), may_alias, aligned(4)));
typedef short b16x8 __attribute__((ext_vector_type(8), may_alias));
typedef short b16x4 __attribute__((ext_vector_type(4), may_alias));

__device__ __forceinline__ f32x4 MFMA(b16x8 a, b16x8 b, f32x4 c) {
  return __builtin_amdgcn_mfma_f32_16x16x32_bf16(a, b, c, 0, 0, 0);
}

__device__ __forceinline__ short f2bf(float f) {
  unsigned u = __builtin_bit_cast(unsigned, f);
  u += 0x7FFFu + ((u >> 16) & 1u);  // round-to-nearest-even
  return (short)(u >> 16);
}

// XOR swizzle for [64][192] bf16 tiles (granule 8 shorts = 16B), bijective.
__device__ __forceinline__ int swz(int row, int col) {
  return row * CDIM + (col ^ ((row & 7) << 3));
}
// [16][32] P scratch: mix row bits 0-1 and 2-3 (R8-verified conflict-safe).
__device__ __forceinline__ int ps(int r, int c) {
  return r * 32 + (c ^ ((((r & 3) ^ ((r >> 2) & 3)) & 3) << 3));
}

// ---- prep 1: fp32 weights -> bf16 ws. Wq pre-scaled by D^-0.5 ----
__global__ void prep_w(const float* __restrict__ Wq, const float* __restrict__ Wkv,
                       const float* __restrict__ Wo, short* __restrict__ wsW) {
  const float scale = 0.17677669529663687f;
  int i = blockIdx.x * 256 + threadIdx.x;
  if (i >= 147456) return;
  float v;
  if (i < 36864)        v = Wq[i] * scale;
  else if (i < 110592)  v = Wkv[i - 36864];
  else                  v = Wo[i - 110592];
  wsW[i] = f2bf(v);
}

// ---- prep 2: rel-pos-bias [6][49][64] f32; k-pad (49..63) = -1e9 mask ----
// (R8-verified: bakes the k-range mask so the hot loop has no branches)
__global__ void prep_bias(const float* __restrict__ rpb, float* __restrict__ bias_t) {
  int idx = blockIdx.x * 256 + threadIdx.x;
  if (idx >= NHEAD * NTOK * 64) return;
  int k = idx & 63;
  int q = (idx >> 6) % NTOK;
  int h = idx / (NTOK * 64);
  float v = -1e9f;
  if (k < NTOK) {
    int ci = (q / 7) * 13 + (q % 7);
    int jj = 48 - k;
    int cj = (jj / 7) * 13 + (jj % 7);
    v = rpb[(ci + cj) * NHEAD + h];
  }
  bias_t[idx] = v;
}

// Fused window-MSA — R12/R14 champion structure (889 us, zero spill, VGPR=64)
// with R8-verified swapped-QK attention transplanted in, 7 barriers (was 8).
// REGISTER CLIFF (R6-R13 law): waves/SIMD ~ 512/(VGPRgranule+AGPR); VGPR must
// stay <=64 — 68 VGPR halved occupancy (R13). Do not add live state.
// LDS (shorts): SH [0,12288) | VT [12288,25344) | KH [25344,37632).
// SH: q stage -> kv stage -> per-wave P scratch.  KH: qh bounce -> kh -> x.
// VT: vhT.  BF epilogue overlays SH+VT.
// Swapped QK^T (mfma(K,Q)): lane l15 owns q-row R*16+l15 -> in-lane softmax
// (15 fmax + shfl 16,32); k>=49 masked by bias-table -1e9 padding.
__global__ __attribute__((amdgpu_flat_work_group_size(512, 512),
                          amdgpu_waves_per_eu(3))) void wmsa_kernel(
    const float* __restrict__ qg, const float* __restrict__ kvg,
    const float* __restrict__ maskg, const float* __restrict__ bq,
    const float* __restrict__ bkv, const float* __restrict__ bo,
    const short* __restrict__ wsW, const float* __restrict__ bias_t,
    float* __restrict__ outg, int nW) {
  __shared__ short lds[37632];     // 75264 B
  short* SH = lds;                 // [64][192] swizzled
  short* VT = lds + 12288;         // [192][68] vhT[c][token]
  short* KH = lds + 25344;         // [64][192] swizzled
  float* BF = (float*)lds;         // epilogue bounce [49][204] f32 (40 KB)

  const int b = blockIdx.x;
  const int tid = threadIdx.x;
  const int w = tid >> 6;          // wave 0..7
  const int lane = tid & 63;
  const int l15 = lane & 15;
  const int lg = lane >> 4;
  const int R = w >> 1, hw = w & 1, h0 = hw * 3;
  const float scale = 0.17677669529663687f;
  const f32x4 zero4 = {0.f, 0.f, 0.f, 0.f};

  const short* WqB = wsW;
  const short* WkvB = wsW + 36864;
  const short* WoB = wsW + 110592;

  const float* qsrc = qg + (size_t)b * (NTOK * CDIM);
  const float* kvsrc = kvg + (size_t)b * (NTOK * CDIM);

  const int qrow = R * 16 + l15;
  const int qc = qrow > 48 ? 48 : qrow;  // pad lanes -> row 48 (outputs unused)

  // ---- issue q and kv loads up front (HBM latency hidden under staging+q-proj) ----
  f32x4 qv[6], kvreg[6];
#pragma unroll
  for (int it = 0; it < 6; ++it) {
    int idx = tid + it * 512;
    int r = idx / 48, c4 = idx % 48;
    qv[it] = (r < NTOK) ? *(const f32x4*)(qsrc + r * CDIM + c4 * 4) : zero4;
  }
#pragma unroll
  for (int it = 0; it < 6; ++it) {
    int idx = tid + it * 512;
    int r = idx / 48, c4 = idx % 48;
    kvreg[it] = (r < NTOK) ? *(const f32x4*)(kvsrc + r * CDIM + c4 * 4) : zero4;
  }
  // ---- stage q -> SH bf16 (rows 49..63 zero) ----
#pragma unroll
  for (int it = 0; it < 6; ++it) {
    int idx = tid + it * 512;
    int r = idx / 48, c4 = idx % 48;
    b16x4 o = {f2bf(qv[it][0]), f2bf(qv[it][1]), f2bf(qv[it][2]), f2bf(qv[it][3])};
    *(b16x4*)(SH + swz(r, c4 * 4)) = o;
  }
  __syncthreads();  // B1: q staged

  // ---- q projection: wave computes exactly its own attention q-tile ----
  f32x4 qacc[6];
#pragma unroll
  for (int t = 0; t < 6; ++t) qacc[t] = zero4;
  {
    b16x8 aq6[6];
#pragma unroll
    for (int kk = 0; kk < 6; ++kk)
      aq6[kk] = *(const b16x8*)(SH + swz(R * 16 + l15, kk * 32 + lg * 8));
#pragma unroll
    for (int t = 0; t < 6; ++t) {
      const int col = (hw * 6 + t) * 16 + l15;
#pragma unroll
      for (int kk = 0; kk < 6; ++kk) {
        b16x8 bw = *(const b16x8*)(WqB + col * CDIM + kk * 32 + lg * 8);
        qacc[t] = MFMA(aq6[kk], bw, qacc[t]);
      }
    }
  }
  // ---- qh -> KH bounce (KH dead until kv-proj; own-wave RAW ordered, so
  // the aq readback needs NO barrier — this removes champion's B3) ----
#pragma unroll
  for (int t = 0; t < 6; ++t) {
    const int col = (hw * 6 + t) * 16 + l15;
    const float bias = bq[col] * scale;
#pragma unroll
    for (int r = 0; r < 4; ++r)
      KH[swz(R * 16 + lg * 4 + r, hw * 96 + t * 16 + l15)] = f2bf(qacc[t][r] + bias);
  }
  b16x8 aq[3];
#pragma unroll
  for (int hh = 0; hh < 3; ++hh)
    aq[hh] = *(const b16x8*)(KH + swz(R * 16 + l15, hw * 96 + hh * 32 + lg * 8));
  __syncthreads();  // B2: q-proj SH reads done (SH free); aq readbacks done

  // ---- stage kv (from regs) -> SH ----
#pragma unroll
  for (int it = 0; it < 6; ++it) {
    int idx = tid + it * 512;
    int r = idx / 48, c4 = idx % 48;
    b16x4 o = {f2bf(kvreg[it][0]), f2bf(kvreg[it][1]), f2bf(kvreg[it][2]),
               f2bf(kvreg[it][3])};
    *(b16x4*)(SH + swz(r, c4 * 4)) = o;
  }
  __syncthreads();  // B3: kv staged

  // ---- kv projection: 24 col-tiles, wave w -> nt = w*3 + {0,1,2} ----
#pragma unroll
  for (int jj = 0; jj < 3; ++jj) {
    const int nt = w * 3 + jj;
    const int col = nt * 16 + l15;  // 0..383
    f32x4 acc[4];
#pragma unroll
    for (int m = 0; m < 4; ++m) acc[m] = zero4;
#pragma unroll
    for (int kk = 0; kk < 6; ++kk) {
      b16x8 bw = *(const b16x8*)(WkvB + col * CDIM + kk * 32 + lg * 8);
#pragma unroll
      for (int m = 0; m < 4; ++m) {
        b16x8 a = *(const b16x8*)(SH + swz(m * 16 + l15, kk * 32 + lg * 8));
        acc[m] = MFMA(a, bw, acc[m]);
      }
    }
    const float bias = bkv[col];
    if (col < CDIM) {  // K half -> KH[token][col]
#pragma unroll
      for (int m = 0; m < 4; ++m)
#pragma unroll
        for (int r = 0; r < 4; ++r)
          KH[swz(m * 16 + lg * 4 + r, col)] = f2bf(acc[m][r] + bias);
    } else {  // V half -> VT[c][token]
      const int c = col - CDIM;
#pragma unroll
      for (int m = 0; m < 4; ++m) {
        b16x4 o = {f2bf(acc[m][0] + bias), f2bf(acc[m][1] + bias),
                   f2bf(acc[m][2] + bias), f2bf(acc[m][3] + bias)};
        *(b16x4*)(VT + c * 68 + m * 16 + lg * 4) = o;
      }
    }
  }
  __syncthreads();  // B4: kh/vT ready; SH kv dead -> P scratch

  // ---- attention (R8-verified swapped mechanics): lane l15 owns q-row qc ----
  const float* maskw = maskg + (size_t)(b % nW) * (NTOK * NTOK);
  f32x4 maskv[3];
#pragma unroll
  for (int nt = 0; nt < 3; ++nt)
    maskv[nt] = *(const f32x4u*)(maskw + qc * NTOK + nt * 16 + lg * 4);
  const float mask48 = (lg == 0) ? maskw[qc * NTOK + 48] : 0.f;

  f32x4 xh[3][2];
#pragma unroll
  for (int hh = 0; hh < 3; ++hh) {
    xh[hh][0] = zero4;
    xh[hh][1] = zero4;
  }
#pragma unroll
  for (int hh = 0; hh < 3; ++hh) {
    const int h = h0 + hh;
    f32x4 Ls[4];
    __builtin_amdgcn_s_setprio(1);
#pragma unroll
    for (int nt = 0; nt < 4; ++nt) {
      b16x8 bk = *(const b16x8*)(KH + swz(nt * 16 + l15, h * 32 + lg * 8));
      Ls[nt] = MFMA(bk, aq[hh], zero4);  // swapped: D col = q-row l15
    }
    __builtin_amdgcn_s_setprio(0);
    // bias (k-padded -1e9) + window mask, all vectorized, no branches
    const float* bt = bias_t + (h * NTOK + qc) * 64;
#pragma unroll
    for (int nt = 0; nt < 4; ++nt) {
      f32x4 bb = *(const f32x4*)(bt + nt * 16 + lg * 4);
#pragma unroll
      for (int rr = 0; rr < 4; ++rr) Ls[nt][rr] += bb[rr];
    }
#pragma unroll
    for (int nt = 0; nt < 3; ++nt)
#pragma unroll
      for (int rr = 0; rr < 4; ++rr) Ls[nt][rr] += maskv[nt][rr];
    Ls[3][0] += mask48;  // k=48 (lg==0); other lanes add 0, k>=49 has -1e9 bias

    // in-lane softmax: 15 fmax + shfl(16,32); row lives in this lane
    float mx = Ls[0][0];
#pragma unroll
    for (int nt = 0; nt < 4; ++nt)
#pragma unroll
      for (int rr = 0; rr < 4; ++rr) mx = fmaxf(mx, Ls[nt][rr]);
    mx = fmaxf(mx, __shfl_xor(mx, 16));
    mx = fmaxf(mx, __shfl_xor(mx, 32));
    float sum = 0.f;
#pragma unroll
    for (int nt = 0; nt < 4; ++nt)
#pragma unroll
      for (int rr = 0; rr < 4; ++rr) {
        Ls[nt][rr] = __expf(Ls[nt][rr] - mx);
        sum += Ls[nt][rr];
      }
    sum += __shfl_xor(sum, 16);
    sum += __shfl_xor(sum, 32);
    const float inv = 1.f / sum;

    // P -> per-wave scratch in dead-SH (ps swizzle), two 32-k halves; PV
    short* Pscr = SH + w * 512;
    b16x8 ap[2];
#pragma unroll
    for (int kkh = 0; kkh < 2; ++kkh) {
#pragma unroll
      for (int nth = 0; nth < 2; ++nth) {
        const int nt = 2 * kkh + nth;
        b16x4 o = {f2bf(Ls[nt][0] * inv), f2bf(Ls[nt][1] * inv),
                   f2bf(Ls[nt][2] * inv), f2bf(Ls[nt][3] * inv)};
        *(b16x4*)(Pscr + ps(l15, nth * 16 + lg * 4)) = o;
      }
      ap[kkh] = *(const b16x8*)(Pscr + ps(l15, lg * 8));
    }
    __builtin_amdgcn_s_setprio(1);
#pragma unroll
    for (int kkh = 0; kkh < 2; ++kkh)
#pragma unroll
      for (int nv = 0; nv < 2; ++nv) {
        b16x8 bv = *(const b16x8*)(VT + (h * 32 + nv * 16 + l15) * 68 + kkh * 32 + lg * 8);
        xh[hh][nv] = MFMA(ap[kkh], bv, xh[hh][nv]);
      }
    __builtin_amdgcn_s_setprio(0);
  }
  __syncthreads();  // B5: all KH/VT/SH-P reads done
  // ---- x -> KH ----
#pragma unroll
  for (int hh = 0; hh < 3; ++hh)
#pragma unroll
    for (int nv = 0; nv < 2; ++nv)
#pragma unroll
      for (int r = 0; r < 4; ++r)
        KH[swz(R * 16 + lg * 4 + r, (h0 + hh) * 32 + nv * 16 + l15)] =
            f2bf(xh[hh][nv][r]);
  __syncthreads();  // B6: x ready (SH, VT dead -> bounce region)

  // ---- output projection -> f32 bounce (stride 204) ----
#pragma unroll
  for (int t = 0; t < 6; ++t) {
    const int pid = w * 6 + t;
    const int j = pid >> 2, m = pid & 3;
    const int col = j * 16 + l15;
    f32x4 oacc = zero4;
#pragma unroll
    for (int kk = 0; kk < 6; ++kk) {
      b16x8 a = *(const b16x8*)(KH + swz(m * 16 + l15, kk * 32 + lg * 8));
      b16x8 bw = *(const b16x8*)(WoB + col * CDIM + kk * 32 + lg * 8);
      oacc = MFMA(a, bw, oacc);
    }
    const float bias = bo[col];
#pragma unroll
    for (int r = 0; r < 4; ++r) {
      const int row = m * 16 + lg * 4 + r;
      if (row < NTOK) BF[row * 204 + col] = oacc[r] + bias;
    }
  }
  __syncthreads();  // B7: bounce ready

  // ---- fully coalesced output stores (16B/lane contiguous) ----
  float* dst = outg + (size_t)b * (NTOK * CDIM);
#pragma unroll
  for (int t = 0; t < 5; ++t) {
    int idx = tid + t * 512;
    if (idx < NTOK * 48) {
      int row = idx / 48, c4 = idx % 48;
      f32x4 v = *(const f32x4*)(BF + row * 204 + c4 * 4);
      *(f32x4*)(dst + row * CDIM + c4 * 4) = v;
    }
  }
}

extern "C" void kernel_launch(void* const* d_in, const int* in_sizes, int n_in,
                              void* d_out, int out_size, void* d_ws, size_t ws_size,
                              hipStream_t stream) {
  const float* q = (const float*)d_in[0];
  const float* kv = (const float*)d_in[1];
  const float* mask = (const float*)d_in[2];
  const float* Wq = (const float*)d_in[3];
  const float* bq = (const float*)d_in[4];
  const float* Wkv = (const float*)d_in[5];
  const float* bkv = (const float*)d_in[6];
  const float* Wo = (const float*)d_in[7];
  const float* bo = (const float*)d_in[8];
  const float* rpb = (const float*)d_in[9];
  short* wsW = (short*)d_ws;
  float* bias_t = (float*)((char*)d_ws + 294912);  // [6][49][64] f32, 75264 B

  const int B = in_sizes[0] / (NTOK * CDIM);
  const int nW = in_sizes[2] / (NTOK * NTOK);

  prep_w<<<576, 256, 0, stream>>>(Wq, Wkv, Wo, wsW);
  prep_bias<<<(NHEAD * NTOK * 64 + 255) / 256, 256, 0, stream>>>(rpb, bias_t);
  wmsa_kernel<<<B, 512, 0, stream>>>(q, kv, mask, bq, bkv, bo, wsW, bias_t,
                                     (float*)d_out, nW);
}